// Round 11
// baseline (73.258 us; speedup 1.0000x reference)
//
#include <hip/hip_runtime.h>
#include <math.h>

#define P 4
#define L 512
#define D 64
#define NC 4
#define RS 68          // LDS row stride (floats): 16B-aligned; conflict-free read patterns
#define SHIFT 64.0f    // fixed softmax shift: s<=0, typical s ~ -72±7; exp(SHIFT+s) stays normal f32
#define NBLK 512       // P * 8(jb) * 16(kh) region blocks, 64j x 32k each

// ws float offsets (~4.3 MB used; every slot written before read -> poison-safe)
#define ROWP_O 0            // rowsum partials [P][16(kh)][512(j)]
#define COLP_O 32768        // colsum partials [P][8(jb)][512(k)]
#define ACC_O  49152        // per-pair (cs,cc) atomics; pair p at ACC_O + p*32 (128B line spread)
#define CNT_O  49280        // int completion counter, own cache line
#define SV_O   49664        // sv spill [512 blocks][256 tid][8]  (4 MiB)

// K1: stage 64-row j-tile + 32-row k-tile, ONE dist sweep (2j x 4k per thread),
// publish row/col partial sums of e = exp(SHIFT - d), spill sv.
// 26 KB LDS -> 2 blocks/CU. Block 0 zero-inits K2's atomics (dispatch boundary
// publishes them device-wide).
__global__ __launch_bounds__(256, 2) void dist_stats(const float* __restrict__ z,
                                                     float* __restrict__ ws) {
    const int bx = blockIdx.x;
    const int pair = bx >> 7, jb = (bx >> 4) & 7, kh = bx & 15;
    const int tid = threadIdx.x;
    const int tx = tid & 7;            // k-group
    const int ty = tid >> 3;           // j-position [0,32)
    const int wave = tid >> 6, lane = tid & 63;

    if (bx == 0) {
        if (tid < 4) { ws[ACC_O + tid * 32] = 0.0f; ws[ACC_O + tid * 32 + 1] = 0.0f; }
        else if (tid == 4) ((int*)(ws + CNT_O))[0] = 0;
    }

    __shared__ float jt[64][RS];       // z0 rows jb*64 .. +64
    __shared__ float kt[32][RS];       // z1 rows kh*32 .. +32
    __shared__ float csred[4][32];

    // stage (coalesced float4): jt 1024 f4 (4/thread), kt 512 f4 (2/thread)
    {
        const float4* z0t = (const float4*)(z + ((size_t)pair * L + jb * 64) * D);
        const float4* z1t = (const float4*)(z + ((size_t)(P + pair) * L + kh * 32) * D);
        #pragma unroll
        for (int i = 0; i < 4; ++i) {
            const int li = i * 256 + tid;
            *(float4*)&jt[li >> 4][(li & 15) * 4] = z0t[li];
        }
        #pragma unroll
        for (int i = 0; i < 2; ++i) {
            const int li = i * 256 + tid;
            *(float4*)&kt[li >> 4][(li & 15) * 4] = z1t[li];
        }
    }
    __syncthreads();

    // dist sweep: acc[r][q] = sum_d |jt[ty+32r][d] - kt[tx+8q][d]|
    float acc[2][4];
    #pragma unroll
    for (int r = 0; r < 2; ++r)
        #pragma unroll
        for (int q = 0; q < 4; ++q) acc[r][q] = 0.f;
    #pragma unroll
    for (int c = 0; c < 16; ++c) {
        float4 jv[2], kv[4];
        #pragma unroll
        for (int r = 0; r < 2; ++r) jv[r] = *(const float4*)&jt[ty + 32 * r][c * 4];
        #pragma unroll
        for (int q = 0; q < 4; ++q) kv[q] = *(const float4*)&kt[tx + 8 * q][c * 4];
        #pragma unroll
        for (int r = 0; r < 2; ++r)
            #pragma unroll
            for (int q = 0; q < 4; ++q)
                acc[r][q] += fabsf(jv[r].x - kv[q].x) + fabsf(jv[r].y - kv[q].y)
                           + fabsf(jv[r].z - kv[q].z) + fabsf(jv[r].w - kv[q].w);
    }

    // spill sv = -acc, per-thread-contiguous 8 floats (2x dwordx4)
    {
        float4* svb = (float4*)(ws + SV_O + (size_t)bx * 2048 + tid * 8);
        #pragma unroll
        for (int r = 0; r < 2; ++r) {
            float4 v;
            v.x = -acc[r][0]; v.y = -acc[r][1]; v.z = -acc[r][2]; v.w = -acc[r][3];
            svb[r] = v;
        }
    }

    // e-sums
    float rs_[2] = {0.f, 0.f};               // per j = ty+32r, over this block's 32 k
    float cs_[4] = {0.f, 0.f, 0.f, 0.f};     // per k = tx+8q, over this block's 64 j
    #pragma unroll
    for (int r = 0; r < 2; ++r)
        #pragma unroll
        for (int q = 0; q < 4; ++q) {
            const float e = __expf(SHIFT - acc[r][q]);
            rs_[r] += e;
            cs_[q] += e;
        }
    // rowsum: reduce over tx (lane bits 0..2)
    #pragma unroll
    for (int off = 1; off <= 4; off <<= 1)
        #pragma unroll
        for (int r = 0; r < 2; ++r) rs_[r] += __shfl_xor(rs_[r], off);
    if (tx == 0) {
        #pragma unroll
        for (int r = 0; r < 2; ++r)
            ws[ROWP_O + (pair * 16 + kh) * 512 + jb * 64 + ty + 32 * r] = rs_[r];
    }
    // colsum: reduce over ty-in-wave (lane bits 3..5), cross-wave via LDS
    #pragma unroll
    for (int off = 8; off <= 32; off <<= 1)
        #pragma unroll
        for (int q = 0; q < 4; ++q) cs_[q] += __shfl_xor(cs_[q], off);
    if (lane < 8) {
        #pragma unroll
        for (int q = 0; q < 4; ++q) csred[wave][tx + 8 * q] = cs_[q];
    }
    __syncthreads();
    if (tid < 32)
        ws[COLP_O + (pair * 8 + jb) * 512 + kh * 32 + tid]
            = csred[0][tid] + csred[1][tid] + csred[2][tid] + csred[3][tid];
}

// K2: reciprocals from partials, re-read sv, accumulate c*s and c; per-pair
// totals combined via line-spread device atomics (RMW-only cross-block
// dataflow, NO threadfence); counter-elected last block writes the logits.
__global__ __launch_bounds__(256) void c_accum_final(float* __restrict__ ws,
                                                     const float* __restrict__ w,
                                                     const float* __restrict__ bias,
                                                     float* __restrict__ out) {
    const int bx = blockIdx.x;
    const int pair = bx >> 7, jb = (bx >> 4) & 7, kh = bx & 15;
    const int tid = threadIdx.x;
    const int tx = tid & 7, ty = tid >> 3;
    const int wave = tid >> 6, lane = tid & 63;

    __shared__ float rrcp_s[64], crcp_s[32];
    __shared__ float bred[4][2];
    __shared__ int   last_flag;
    __shared__ float totals[8];

    if (tid < 64) {                       // rowsum for j = jb*64 + tid: 16 partials
        float s = 0.f;
        #pragma unroll
        for (int h = 0; h < 16; ++h)
            s += ws[ROWP_O + (pair * 16 + h) * 512 + jb * 64 + tid];
        rrcp_s[tid] = 1.0f / s;
    } else if (tid < 96) {                // colsum for k = kh*32 + (tid-64): 8 partials
        const int kl = tid - 64;
        float s = 0.f;
        #pragma unroll
        for (int b = 0; b < 8; ++b)
            s += ws[COLP_O + (pair * 8 + b) * 512 + kh * 32 + kl];
        crcp_s[kl] = 1.0f / s;
    }
    __syncthreads();

    const float4* svb = (const float4*)(ws + SV_O + (size_t)bx * 2048 + tid * 8);
    float cs = 0.f, cc = 0.f;
    #pragma unroll
    for (int r = 0; r < 2; ++r) {
        const float rr = rrcp_s[ty + 32 * r];
        const float4 sv4 = svb[r];
        const float svs[4] = {sv4.x, sv4.y, sv4.z, sv4.w};
        #pragma unroll
        for (int q = 0; q < 4; ++q) {
            const float cr = crcp_s[tx + 8 * q];
            const float sv = svs[q];
            const float e  = __expf(SHIFT + sv);
            const float a  = e * rr;
            const float b  = e * cr;
            const float c  = a + b - a * b;
            cs += c * sv;
            cc += c;
        }
    }
    #pragma unroll
    for (int off = 1; off <= 32; off <<= 1) {
        cs += __shfl_xor(cs, off);
        cc += __shfl_xor(cc, off);
    }
    if (lane == 0) { bred[wave][0] = cs; bred[wave][1] = cc; }
    __syncthreads();

    if (tid == 0) {
        const float bcs = bred[0][0] + bred[1][0] + bred[2][0] + bred[3][0];
        const float bcc = bred[0][1] + bred[1][1] + bred[2][1] + bred[3][1];
        atomicAdd(&ws[ACC_O + pair * 32],     bcs);   // device-scope RMW at coherence point
        atomicAdd(&ws[ACC_O + pair * 32 + 1], bcc);
        __builtin_amdgcn_s_waitcnt(0);                // adds globally performed before counter
        const int old = atomicAdd((int*)(ws + CNT_O), 1);
        last_flag = (old == NBLK - 1) ? 1 : 0;
    }
    __syncthreads();

    if (last_flag) {
        if (tid < 8)                                  // RMW-read at the coherence point
            totals[tid] = atomicAdd(&ws[ACC_O + (tid >> 1) * 32 + (tid & 1)], 0.0f);
        __syncthreads();
        if (tid < P) {
            const float c_val = totals[tid * 2] / totals[tid * 2 + 1];
            #pragma unroll
            for (int cls = 0; cls < NC; ++cls)
                out[tid * NC + cls] = c_val * w[cls] + bias[cls];
        }
    }
}

extern "C" void kernel_launch(void* const* d_in, const int* in_sizes, int n_in,
                              void* d_out, int out_size, void* d_ws, size_t ws_size,
                              hipStream_t stream) {
    const float* z    = (const float*)d_in[0];   // (2P, L, D) f32
    const float* w    = (const float*)d_in[1];   // (1, NC) f32
    const float* bias = (const float*)d_in[2];   // (NC,) f32
    float* out = (float*)d_out;                  // (P, NC) f32
    float* ws  = (float*)d_ws;                   // ~4.3 MB used

    dist_stats   <<<dim3(NBLK), dim3(256), 0, stream>>>(z, ws);
    c_accum_final<<<dim3(NBLK), dim3(256), 0, stream>>>(ws, w, bias, out);
}

// Round 12
// 70.620 us; speedup vs baseline: 1.0374x; 1.0374x over previous
//
#include <hip/hip_runtime.h>
#include <math.h>

#define P 4
#define L 512
#define D 64
#define NC 4
#define RS 68          // LDS row stride (floats): 16B-aligned; conflict-free read patterns
#define SHIFT 64.0f    // fixed softmax shift: s<=0, typical s ~ -72±7; exp(SHIFT+s) stays normal f32
#define NBLK 512       // K1: P * 8(jb) * 16(kh) region blocks, 64j x 32k each

// ws float offsets (~4.3 MB used; every slot written before read -> poison-safe)
#define ROWP_O 0            // rowsum partials [P][16(kh)][512(j)]
#define COLP_O 32768        // colsum partials [P][8(jb)][512(k)]
#define ACC_O  49152        // per-pair (cs,cc) atomics; pair p at ACC_O + p*32 (128B line spread)
#define CNT_O  49280        // per-pair int counters; pair p at int slot p*32 (128B line spread)
#define SV_O   49664        // sv spill [512 K1-blocks][2048]  (4 MiB)

// K1: stage 64-row j-tile + 32-row k-tile, ONE dist sweep (2j x 4k per thread),
// publish row/col partial sums of e = exp(SHIFT - d), spill sv.
// Block 0 zero-inits K2's atomics (dispatch boundary publishes them device-wide).
__global__ __launch_bounds__(256, 2) void dist_stats(const float* __restrict__ z,
                                                     float* __restrict__ ws) {
    const int bx = blockIdx.x;
    const int pair = bx >> 7, jb = (bx >> 4) & 7, kh = bx & 15;
    const int tid = threadIdx.x;
    const int tx = tid & 7;            // k-group
    const int ty = tid >> 3;           // j-position [0,32)
    const int wave = tid >> 6, lane = tid & 63;

    if (bx == 0) {
        if (tid < 4) { ws[ACC_O + tid * 32] = 0.0f; ws[ACC_O + tid * 32 + 1] = 0.0f; }
        else if (tid < 8) ((int*)(ws + CNT_O))[(tid - 4) * 32] = 0;
    }

    __shared__ float jt[64][RS];       // z0 rows jb*64 .. +64
    __shared__ float kt[32][RS];       // z1 rows kh*32 .. +32
    __shared__ float csred[4][32];

    // stage (coalesced float4): jt 1024 f4 (4/thread), kt 512 f4 (2/thread)
    {
        const float4* z0t = (const float4*)(z + ((size_t)pair * L + jb * 64) * D);
        const float4* z1t = (const float4*)(z + ((size_t)(P + pair) * L + kh * 32) * D);
        #pragma unroll
        for (int i = 0; i < 4; ++i) {
            const int li = i * 256 + tid;
            *(float4*)&jt[li >> 4][(li & 15) * 4] = z0t[li];
        }
        #pragma unroll
        for (int i = 0; i < 2; ++i) {
            const int li = i * 256 + tid;
            *(float4*)&kt[li >> 4][(li & 15) * 4] = z1t[li];
        }
    }
    __syncthreads();

    // dist sweep: acc[r][q] = sum_d |jt[ty+32r][d] - kt[tx+8q][d]|
    float acc[2][4];
    #pragma unroll
    for (int r = 0; r < 2; ++r)
        #pragma unroll
        for (int q = 0; q < 4; ++q) acc[r][q] = 0.f;
    #pragma unroll
    for (int c = 0; c < 16; ++c) {
        float4 jv[2], kv[4];
        #pragma unroll
        for (int r = 0; r < 2; ++r) jv[r] = *(const float4*)&jt[ty + 32 * r][c * 4];
        #pragma unroll
        for (int q = 0; q < 4; ++q) kv[q] = *(const float4*)&kt[tx + 8 * q][c * 4];
        #pragma unroll
        for (int r = 0; r < 2; ++r)
            #pragma unroll
            for (int q = 0; q < 4; ++q)
                acc[r][q] += fabsf(jv[r].x - kv[q].x) + fabsf(jv[r].y - kv[q].y)
                           + fabsf(jv[r].z - kv[q].z) + fabsf(jv[r].w - kv[q].w);
    }

    // spill sv = -acc, per-thread-contiguous 8 floats (2x dwordx4)
    // float index f = tid*8 + r*4 + q  <->  j = jb*64 + (tid>>3) + 32r, k = kh*32 + (tid&7) + 8q
    {
        float4* svb = (float4*)(ws + SV_O + (size_t)bx * 2048 + tid * 8);
        #pragma unroll
        for (int r = 0; r < 2; ++r) {
            float4 v;
            v.x = -acc[r][0]; v.y = -acc[r][1]; v.z = -acc[r][2]; v.w = -acc[r][3];
            svb[r] = v;
        }
    }

    // e-sums
    float rs_[2] = {0.f, 0.f};               // per j = ty+32r, over this block's 32 k
    float cs_[4] = {0.f, 0.f, 0.f, 0.f};     // per k = tx+8q, over this block's 64 j
    #pragma unroll
    for (int r = 0; r < 2; ++r)
        #pragma unroll
        for (int q = 0; q < 4; ++q) {
            const float e = __expf(SHIFT - acc[r][q]);
            rs_[r] += e;
            cs_[q] += e;
        }
    // rowsum: reduce over tx (lane bits 0..2)
    #pragma unroll
    for (int off = 1; off <= 4; off <<= 1)
        #pragma unroll
        for (int r = 0; r < 2; ++r) rs_[r] += __shfl_xor(rs_[r], off);
    if (tx == 0) {
        #pragma unroll
        for (int r = 0; r < 2; ++r)
            ws[ROWP_O + (pair * 16 + kh) * 512 + jb * 64 + ty + 32 * r] = rs_[r];
    }
    // colsum: reduce over ty-in-wave (lane bits 3..5), cross-wave via LDS
    #pragma unroll
    for (int off = 8; off <= 32; off <<= 1)
        #pragma unroll
        for (int q = 0; q < 4; ++q) cs_[q] += __shfl_xor(cs_[q], off);
    if (lane < 8) {
        #pragma unroll
        for (int q = 0; q < 4; ++q) csred[wave][tx + 8 * q] = cs_[q];
    }
    __syncthreads();
    if (tid < 32)
        ws[COLP_O + (pair * 8 + jb) * 512 + kh * 32 + tid]
            = csred[0][tid] + csred[1][tid] + csred[2][tid] + csred[3][tid];
}

// K2: 64 blocks = 16 per pair (kh-chunked). Build rrcp (all 512 j) + crcp
// (this chunk's 32 k) in LDS, sweep 8 jb sub-blocks of sv, reduce, combine
// per pair via line-spread RMW atomics with PER-PAIR counters (16 RMWs each).
__global__ __launch_bounds__(256) void c_accum_final(float* __restrict__ ws,
                                                     const float* __restrict__ w,
                                                     const float* __restrict__ bias,
                                                     float* __restrict__ out) {
    const int bx = blockIdx.x;
    const int pair = bx >> 4, ch = bx & 15;   // ch = kh chunk
    const int tid = threadIdx.x;
    const int wave = tid >> 6, lane = tid & 63;

    __shared__ float rrcp_s[512];
    __shared__ float crcp_s[32];
    __shared__ float bred[4][2];
    __shared__ int   last_flag;
    __shared__ float totals[2];

    // rrcp for all 512 j (16 kh-partials each); 2 j per thread
    #pragma unroll
    for (int i = 0; i < 2; ++i) {
        const int j = i * 256 + tid;
        float s = 0.f;
        #pragma unroll
        for (int h = 0; h < 16; ++h)
            s += ws[ROWP_O + (pair * 16 + h) * 512 + j];
        rrcp_s[j] = 1.0f / s;
    }
    // crcp for this chunk's 32 k (8 jb-partials each)
    if (tid < 32) {
        float s = 0.f;
        #pragma unroll
        for (int b = 0; b < 8; ++b)
            s += ws[COLP_O + (pair * 8 + b) * 512 + ch * 32 + tid];
        crcp_s[tid] = 1.0f / s;
    }
    __syncthreads();

    // sweep the 8 jb sub-blocks of sv for (pair, ch); 64 floats per thread
    float cs = 0.f, cc = 0.f;
    #pragma unroll
    for (int jb = 0; jb < 8; ++jb) {
        const float4* svb = (const float4*)(ws + SV_O
                            + (size_t)((pair << 7) | (jb << 4) | ch) * 2048);
        #pragma unroll
        for (int i = 0; i < 2; ++i) {
            const int o4 = i * 256 + tid;                 // float4 idx [0,512)
            const float4 sv4 = svb[o4];                   // coalesced
            const int j = jb * 64 + (o4 >> 4) + 32 * (o4 & 1);
            const int kb = (o4 >> 1) & 7;                 // k = ch*32 + kb + 8q
            const float rr = rrcp_s[j];
            const float svs[4] = {sv4.x, sv4.y, sv4.z, sv4.w};
            #pragma unroll
            for (int q = 0; q < 4; ++q) {
                const float cr = crcp_s[kb + 8 * q];
                const float sv = svs[q];
                const float e  = __expf(SHIFT + sv);
                const float a  = e * rr;
                const float b  = e * cr;
                const float c  = a + b - a * b;
                cs += c * sv;
                cc += c;
            }
        }
    }
    #pragma unroll
    for (int off = 1; off <= 32; off <<= 1) {
        cs += __shfl_xor(cs, off);
        cc += __shfl_xor(cc, off);
    }
    if (lane == 0) { bred[wave][0] = cs; bred[wave][1] = cc; }
    __syncthreads();

    if (tid == 0) {
        const float bcs = bred[0][0] + bred[1][0] + bred[2][0] + bred[3][0];
        const float bcc = bred[0][1] + bred[1][1] + bred[2][1] + bred[3][1];
        atomicAdd(&ws[ACC_O + pair * 32],     bcs);   // device-scope RMW, line-spread
        atomicAdd(&ws[ACC_O + pair * 32 + 1], bcc);
        __builtin_amdgcn_s_waitcnt(0);                // adds globally performed first
        const int old = atomicAdd(&((int*)(ws + CNT_O))[pair * 32], 1);
        last_flag = (old == 15) ? 1 : 0;              // last of this pair's 16 blocks
    }
    __syncthreads();

    if (last_flag) {
        if (tid < 2)                                  // RMW-read at the coherence point
            totals[tid] = atomicAdd(&ws[ACC_O + pair * 32 + tid], 0.0f);
        __syncthreads();
        if (tid == 0) {
            const float c_val = totals[0] / totals[1];
            #pragma unroll
            for (int cls = 0; cls < NC; ++cls)
                out[pair * NC + cls] = c_val * w[cls] + bias[cls];
        }
    }
}

extern "C" void kernel_launch(void* const* d_in, const int* in_sizes, int n_in,
                              void* d_out, int out_size, void* d_ws, size_t ws_size,
                              hipStream_t stream) {
    const float* z    = (const float*)d_in[0];   // (2P, L, D) f32
    const float* w    = (const float*)d_in[1];   // (1, NC) f32
    const float* bias = (const float*)d_in[2];   // (NC,) f32
    float* out = (float*)d_out;                  // (P, NC) f32
    float* ws  = (float*)d_ws;                   // ~4.3 MB used

    dist_stats   <<<dim3(NBLK),  dim3(256), 0, stream>>>(z, ws);
    c_accum_final<<<dim3(P * 16), dim3(256), 0, stream>>>(ws, w, bias, out);
}